// Round 14
// baseline (822.199 us; speedup 1.0000x reference)
//
#include <hip/hip_runtime.h>
#include <hip/hip_bf16.h>
#include <hip/hip_cooperative_groups.h>

namespace cg = cooperative_groups;

// Problem constants (fixed by the reference)
#define NN 50000      // nodes
#define EE 800000     // raw edges
#define TE 850000     // edges + self loops
#define NCH 196       // ceil(NN/256) chunks for the scan
#define PAIRS ((TE + 1) / 2)
#define CGRID 1024    // cooperative grid (co-resident: 4 blocks/CU)

typedef __hip_bfloat16 bf16;
typedef __attribute__((ext_vector_type(8))) short short8v;   // 8 bf16 = 4 VGPR
typedef __attribute__((ext_vector_type(4))) float float4v;   // MFMA C/D

__device__ __forceinline__ float b2f(bf16 v) { return __bfloat162float(v); }
__device__ __forceinline__ float bu2f(unsigned short v) {
    return __uint_as_float((unsigned)v << 16);
}
__device__ __forceinline__ unsigned short f2bu(float v) {
    bf16 t = __float2bfloat16(v);
    return *(unsigned short*)&t;
}
__device__ __forceinline__ float lrelu(float e) { return (e > 0.f) ? e : 0.2f * e; }
__device__ __forceinline__ int clampn(int v) {
    return (v < 0) ? 0 : (v >= NN ? NN - 1 : v);
}

// ---------------- cooperative CSR build (1 dispatch replaces 5) -------------
// phase 0: zero deg + weight transposes/projections
// phase 1: degree count (atomicAdd)
// phase 2: two-level exclusive scan -> offs
// phase 3: reverse-fill (atomicSub on deg)
__global__ __launch_bounds__(256) void csr_build_k(
    const void* __restrict__ ei, int* __restrict__ deg, int* __restrict__ offs,
    int* __restrict__ csr_raw, int* __restrict__ chunktot, int* __restrict__ chunkoff,
    const float* __restrict__ W1, const float* __restrict__ W2,
    const float* __restrict__ asr1, const float* __restrict__ ads1,
    const float* __restrict__ asr2, const float* __restrict__ ads2,
    unsigned short* __restrict__ W1T, unsigned short* __restrict__ W2T,
    unsigned short* __restrict__ P1sT, unsigned short* __restrict__ P1dT,
    unsigned short* __restrict__ P2T) {
    cg::grid_group grid = cg::this_grid();
    __shared__ int s[256];
    int b = blockIdx.x, t = threadIdx.x;
    int gt = b * 256 + t;

    // int64 detection (same data every block; no cross-block dependency)
    int isi64;
    {
        unsigned z = (t < 64 && ((const unsigned*)ei)[2 * t + 1] == 0u) ? 1u : 0u;
        unsigned long long mball = __ballot(z);
        isi64 = (__popcll(mball) >= 32) ? 1 : 0;   // uniform across wave 0..3? ballot is per-wave
        // make it block-uniform via LDS
        if (t == 0) s[0] = 0;
        __syncthreads();
        if (t < 64 && z) atomicAdd(&s[0], 1);
        __syncthreads();
        isi64 = (s[0] >= 32) ? 1 : 0;
        __syncthreads();
    }

    // ---- phase 0: zero deg + weight prep ----
    for (int i = gt; i < NN; i += CGRID * 256) deg[i] = 0;
    if (b < 128) {
        int j = b * 256 + t;                 // 32768 W1T entries
        int n = j >> 7, k = j & 127;
        W1T[j] = f2bu(W1[k * 256 + n]);
    } else if (b < 192) {
        int j = (b - 128) * 256 + t;         // 16384 W2T entries
        int n = j >> 8, k = j & 255;
        W2T[j] = f2bu(W2[k * 64 + n]);
    } else if (b == 192) {
        for (int j = t; j < 2048; j += 256) {
            int h = j >> 7, k = j & 127;
            float sv = 0.f, dv = 0.f;
            for (int c = 0; c < 16; ++c) {
                float wv = W1[k * 256 + h * 16 + c];
                sv += wv * asr1[h * 16 + c];
                dv += wv * ads1[h * 16 + c];
            }
            P1sT[j] = f2bu(sv);
            P1dT[j] = f2bu(dv);
        }
    } else if (b == 193) {
        int k = t;
        float sv = 0.f, dv = 0.f;
        for (int c = 0; c < 64; ++c) {
            float wv = W2[k * 64 + c];
            sv += wv * asr2[c];
            dv += wv * ads2[c];
        }
        P2T[k] = f2bu(sv);
        P2T[256 + k] = f2bu(dv);
        for (int j = 512 + t; j < 4096; j += 256) P2T[j] = 0;
    }
    grid.sync();

    // ---- phase 1: degree count (2 edges per thread-iteration) ----
    for (int p = gt; p < PAIRS; p += CGRID * 256) {
        int i0 = p * 2;
        int d0, d1 = -1;
        if (i0 + 1 < EE) {
            if (isi64) {
                longlong2 v = ((const longlong2*)ei)[(EE >> 1) + p];
                d0 = clampn((int)v.x); d1 = clampn((int)v.y);
            } else {
                int2 v = ((const int2*)ei)[(EE >> 1) + p];
                d0 = clampn(v.x); d1 = clampn(v.y);
            }
        } else {
            d0 = (i0 < EE) ? clampn(isi64 ? (int)((const long long*)ei)[EE + i0]
                                          : ((const int*)ei)[EE + i0])
                           : (i0 - EE);
            if (i0 + 1 < TE)
                d1 = (i0 + 1 < EE) ? clampn(isi64 ? (int)((const long long*)ei)[EE + i0 + 1]
                                                  : ((const int*)ei)[EE + i0 + 1])
                                   : (i0 + 1 - EE);
        }
        atomicAdd(&deg[d0], 1);
        if (d1 >= 0) atomicAdd(&deg[d1], 1);
    }
    grid.sync();

    // ---- phase 2a: per-chunk scan; offs gets chunk-local exclusive ----
    if (b < NCH) {
        int i = b * 256 + t;
        int v = (i < NN) ? deg[i] : 0;
        s[t] = v;
        __syncthreads();
        for (int d = 1; d < 256; d <<= 1) {
            int u = (t >= d) ? s[t - d] : 0;
            __syncthreads();
            s[t] += u;
            __syncthreads();
        }
        if (i < NN) offs[i] = s[t] - v;
        if (t == 255) chunktot[b] = s[255];
    }
    grid.sync();

    // ---- phase 2b: block 0 scans the 196 chunk totals (exclusive) ----
    if (b == 0) {
        int v = (t < NCH) ? chunktot[t] : 0;
        s[t] = v;
        __syncthreads();
        for (int d = 1; d < 256; d <<= 1) {
            int u = (t >= d) ? s[t - d] : 0;
            __syncthreads();
            s[t] += u;
            __syncthreads();
        }
        if (t < NCH) chunkoff[t] = s[t] - v;
    }
    grid.sync();

    // ---- phase 2c: apply chunk bases ----
    if (b < NCH) {
        int i = b * 256 + t;
        if (i < NN) offs[i] += chunkoff[b];
        if (b == NCH - 1 && t == 0) offs[NN] = chunkoff[NCH - 1] + chunktot[NCH - 1];
    }
    grid.sync();

    // ---- phase 3: reverse fill ----
    for (int p = gt; p < PAIRS; p += CGRID * 256) {
        int i0 = p * 2;
        int s0, d0, s1 = -1, d1 = -1;
        if (i0 + 1 < EE) {
            if (isi64) {
                longlong2 sv = ((const longlong2*)ei)[p];
                longlong2 dv = ((const longlong2*)ei)[(EE >> 1) + p];
                s0 = clampn((int)sv.x); s1 = clampn((int)sv.y);
                d0 = clampn((int)dv.x); d1 = clampn((int)dv.y);
            } else {
                int2 sv = ((const int2*)ei)[p];
                int2 dv = ((const int2*)ei)[(EE >> 1) + p];
                s0 = clampn(sv.x); s1 = clampn(sv.y);
                d0 = clampn(dv.x); d1 = clampn(dv.y);
            }
        } else {
            auto lde = [&](long long idx) {
                return clampn(isi64 ? (int)((const long long*)ei)[idx]
                                    : ((const int*)ei)[idx]);
            };
            if (i0 < EE) { s0 = lde(i0); d0 = lde((long long)EE + i0); }
            else         { s0 = i0 - EE; d0 = i0 - EE; }
            if (i0 + 1 < TE) {
                if (i0 + 1 < EE) { s1 = lde(i0 + 1); d1 = lde((long long)EE + i0 + 1); }
                else             { s1 = i0 + 1 - EE; d1 = i0 + 1 - EE; }
            }
        }
        int pos0 = offs[d0] + atomicSub(&deg[d0], 1) - 1;
        csr_raw[pos0] = s0;
        if (d1 >= 0) {
            int pos1 = offs[d1] + atomicSub(&deg[d1], 1) - 1;
            csr_raw[pos1] = s1;
        }
    }
}

// ---------------- Layer 1 GEMM on MFMA; alphas via projection MFMAs ---------
__global__ __launch_bounds__(256) void gemm1_k(
    const float* __restrict__ x, const unsigned short* __restrict__ W1T,
    const unsigned short* __restrict__ P1sT, const unsigned short* __restrict__ P1dT,
    bf16* __restrict__ h1, float* __restrict__ a_src, float* __restrict__ a_dst) {
    int wv = threadIdx.x >> 6, lane = threadIdx.x & 63;
    int m = lane & 15, quad = lane >> 4;
    int row0 = blockIdx.x * 64 + wv * 16;
    int arow = row0 + m;
    int arowc = (arow < NN) ? arow : NN - 1;
    const float4* x4 = (const float4*)x;
    short8v a[4];
#pragma unroll
    for (int ks = 0; ks < 4; ++ks) {
        float4 f0 = x4[(size_t)arowc * 32 + ks * 8 + quad * 2];
        float4 f1 = x4[(size_t)arowc * 32 + ks * 8 + quad * 2 + 1];
        union { short8v v; unsigned short u[8]; } ua;
        ua.u[0] = f2bu(f0.x); ua.u[1] = f2bu(f0.y);
        ua.u[2] = f2bu(f0.z); ua.u[3] = f2bu(f0.w);
        ua.u[4] = f2bu(f1.x); ua.u[5] = f2bu(f1.y);
        ua.u[6] = f2bu(f1.z); ua.u[7] = f2bu(f1.w);
        a[ks] = ua.v;
    }
    float4v accs = {0.f, 0.f, 0.f, 0.f}, accd = {0.f, 0.f, 0.f, 0.f};
#pragma unroll
    for (int ks = 0; ks < 4; ++ks) {
        short8v bs = *(const short8v*)&P1sT[(size_t)m * 128 + quad * 8 + ks * 32];
        short8v bd = *(const short8v*)&P1dT[(size_t)m * 128 + quad * 8 + ks * 32];
        accs = __builtin_amdgcn_mfma_f32_16x16x32_bf16(a[ks], bs, accs, 0, 0, 0);
        accd = __builtin_amdgcn_mfma_f32_16x16x32_bf16(a[ks], bd, accd, 0, 0, 0);
    }
    float4v acc[16];
#pragma unroll
    for (int t = 0; t < 16; ++t) {
        float4v c = {0.f, 0.f, 0.f, 0.f};
        const unsigned short* wb = &W1T[(size_t)(t * 16 + m) * 128 + quad * 8];
#pragma unroll
        for (int ks = 0; ks < 4; ++ks) {
            short8v b = *(const short8v*)&wb[ks * 32];
            c = __builtin_amdgcn_mfma_f32_16x16x32_bf16(a[ks], b, c, 0, 0, 0);
        }
        acc[t] = c;
    }
#pragma unroll
    for (int t = 0; t < 16; ++t) {
#pragma unroll
        for (int r = 0; r < 4; ++r) {
            int orow = row0 + quad * 4 + r;
            if (orow < NN)
                h1[(size_t)orow * 256 + t * 16 + m] = __float2bfloat16(acc[t][r]);
        }
    }
#pragma unroll
    for (int r = 0; r < 4; ++r) {
        int orow = row0 + quad * 4 + r;
        if (orow < NN) {
            a_src[orow * 16 + m] = accs[r];   // C col == head == m
            a_dst[orow * 16 + m] = accd[r];
        }
    }
}

// ---------------- Layer 1 aggregation: wave-per-dst, on-the-fly sort --------
__global__ __launch_bounds__(256) void agg1_k(
    const int* __restrict__ offs, const int* __restrict__ csr_raw,
    int* __restrict__ csr_can,
    const float* __restrict__ a_src, const float* __restrict__ a_dst,
    const bf16* __restrict__ h1, const float* __restrict__ b1,
    bf16* __restrict__ out1) {
    __shared__ int sbuf[4][256];
    int wv = threadIdx.x >> 6, lane = threadIdx.x & 63;
    int dst = blockIdx.x * 4 + wv;          // grid = NN/4 exactly
    int start = offs[dst], end = offs[dst + 1];
    int d = end - start;
    if (d <= 64) {
        int v = (lane < d) ? csr_raw[start + lane] : 0x7fffffff;
        int rank = 0;
        for (int j = 0; j < d; ++j) {
            int vj = __shfl(v, j, 64);
            rank += (vj < v || (vj == v && j < lane)) ? 1 : 0;
        }
        if (lane < d) sbuf[wv][rank] = v;
    } else if (d <= 256) {
        if (lane == 0) {
            for (int i = 0; i < d; ++i) {
                int v = csr_raw[start + i];
                int j = i - 1;
                while (j >= 0 && sbuf[wv][j] > v) { sbuf[wv][j + 1] = sbuf[wv][j]; --j; }
                sbuf[wv][j + 1] = v;
            }
        }
    } else {
        for (int i = lane; i < d && i < 256; i += 64) sbuf[wv][i] = csr_raw[start + i];
        if (d > 256) d = 256;
    }
    for (int i = lane; i < d; i += 64) csr_can[start + i] = sbuf[wv][i];
    int we = lane >> 4, wh = lane & 15;
    int hc = lane >> 2;
    float adst_w = a_dst[dst * 16 + wh];
    float ax = 0.f, ay = 0.f, az = 0.f, aw = 0.f;
    float dsum = 0.f;
    int t0 = 0;
    for (; t0 + 4 <= d; t0 += 4) {
        int sr = sbuf[wv][t0 + we];
        float wr = __expf(lrelu(a_src[sr * 16 + wh] + adst_w));
        dsum += wr;
#pragma unroll
        for (int j = 0; j < 4; ++j) {
            float wj = __shfl(wr, j * 16 + hc, 64);
            int sj = sbuf[wv][t0 + j];
            ushort4 hv = *(const ushort4*)&h1[(size_t)sj * 256 + lane * 4];
            ax += wj * bu2f(hv.x);
            ay += wj * bu2f(hv.y);
            az += wj * bu2f(hv.z);
            aw += wj * bu2f(hv.w);
        }
    }
    if (t0 < d) {
        int n = d - t0;
        float wr = 0.f;
        if (we < n) {
            int sr = sbuf[wv][t0 + we];
            wr = __expf(lrelu(a_src[sr * 16 + wh] + adst_w));
        }
        dsum += wr;
        for (int j = 0; j < n; ++j) {
            float wj = __shfl(wr, j * 16 + hc, 64);
            int sj = sbuf[wv][t0 + j];
            ushort4 hv = *(const ushort4*)&h1[(size_t)sj * 256 + lane * 4];
            ax += wj * bu2f(hv.x);
            ay += wj * bu2f(hv.y);
            az += wj * bu2f(hv.z);
            aw += wj * bu2f(hv.w);
        }
    }
    dsum += __shfl_xor(dsum, 16, 64);
    dsum += __shfl_xor(dsum, 32, 64);
    float invd = 1.f / (__shfl(dsum, hc, 64) + 1e-16f);
    float4 bv = *(const float4*)&b1[lane * 4];
    ushort4 st;
    st.x = f2bu(ax * invd + bv.x);
    st.y = f2bu(ay * invd + bv.y);
    st.z = f2bu(az * invd + bv.z);
    st.w = f2bu(aw * invd + bv.w);
    *(ushort4*)&out1[(size_t)dst * 256 + lane * 4] = st;
}

// ---------------- Layer 2 GEMM on MFMA; alphas via packed projection --------
__global__ __launch_bounds__(256) void gemm2_k(
    const bf16* __restrict__ out1, const unsigned short* __restrict__ W2T,
    const unsigned short* __restrict__ P2T,
    bf16* __restrict__ h2, float* __restrict__ a_src2, float* __restrict__ a_dst2) {
    int wv = threadIdx.x >> 6, lane = threadIdx.x & 63;
    int m = lane & 15, quad = lane >> 4;
    int row0 = blockIdx.x * 64 + wv * 16;
    int arow = row0 + m;
    int arowc = (arow < NN) ? arow : NN - 1;
    const unsigned short* ab = (const unsigned short*)out1;
    short8v a[8];
#pragma unroll
    for (int ks = 0; ks < 8; ++ks)
        a[ks] = *(const short8v*)&ab[(size_t)arowc * 256 + ks * 32 + quad * 8];
    float4v acca = {0.f, 0.f, 0.f, 0.f};
#pragma unroll
    for (int ks = 0; ks < 8; ++ks) {
        short8v b = *(const short8v*)&P2T[(size_t)m * 256 + quad * 8 + ks * 32];
        acca = __builtin_amdgcn_mfma_f32_16x16x32_bf16(a[ks], b, acca, 0, 0, 0);
    }
    float4v acc[4];
#pragma unroll
    for (int t = 0; t < 4; ++t) {
        float4v c = {0.f, 0.f, 0.f, 0.f};
        const unsigned short* wb = &W2T[(size_t)(t * 16 + m) * 256 + quad * 8];
#pragma unroll
        for (int ks = 0; ks < 8; ++ks) {
            short8v b = *(const short8v*)&wb[ks * 32];
            c = __builtin_amdgcn_mfma_f32_16x16x32_bf16(a[ks], b, c, 0, 0, 0);
        }
        acc[t] = c;
    }
#pragma unroll
    for (int t = 0; t < 4; ++t) {
#pragma unroll
        for (int r = 0; r < 4; ++r) {
            int orow = row0 + quad * 4 + r;
            if (orow < NN)
                h2[(size_t)orow * 64 + t * 16 + m] = __float2bfloat16(acc[t][r]);
        }
    }
#pragma unroll
    for (int r = 0; r < 4; ++r) {
        int orow = row0 + quad * 4 + r;
        if (orow < NN) {
            if (m == 0) a_src2[orow] = acca[r];   // col 0 = src projection
            if (m == 1) a_dst2[orow] = acca[r];   // col 1 = dst projection
        }
    }
}

// ---------------- Layer 2 aggregation + sigmoid (f32 out) -------------------
__global__ __launch_bounds__(256) void agg2_k(
    const int* __restrict__ offs, const int* __restrict__ csr_src,
    const float* __restrict__ a_src2, const float* __restrict__ a_dst2,
    const bf16* __restrict__ h2, const float* __restrict__ b2,
    float* __restrict__ out) {
    int wv = threadIdx.x >> 6;
    int lane = threadIdx.x & 63;
    int dst = blockIdx.x * 4 + wv;
    if (dst >= NN) return;
    int start = offs[dst], end = offs[dst + 1];
    float adst = a_dst2[dst];
    float acc = 0.f, dsum = 0.f;
    for (int t0 = start; t0 < end; t0 += 64) {
        int n = end - t0; if (n > 64) n = 64;
        float wr = 0.f; int sr = 0;
        if (lane < n) {
            sr = csr_src[t0 + lane];
            wr = __expf(lrelu(a_src2[sr] + adst));
        }
        dsum += wr;
        int j = 0;
        for (; j + 4 <= n; j += 4) {
            float w0 = __shfl(wr, j, 64),     w1 = __shfl(wr, j + 1, 64);
            float w2 = __shfl(wr, j + 2, 64), w3 = __shfl(wr, j + 3, 64);
            int s0 = __shfl(sr, j, 64),       s1 = __shfl(sr, j + 1, 64);
            int s2 = __shfl(sr, j + 2, 64),   s3 = __shfl(sr, j + 3, 64);
            float h0 = b2f(h2[(size_t)s0 * 64 + lane]);
            float h1v = b2f(h2[(size_t)s1 * 64 + lane]);
            float h2v = b2f(h2[(size_t)s2 * 64 + lane]);
            float h3 = b2f(h2[(size_t)s3 * 64 + lane]);
            acc += w0 * h0 + w1 * h1v + w2 * h2v + w3 * h3;
        }
        for (; j < n; ++j) {
            float wj = __shfl(wr, j, 64);
            int sj = __shfl(sr, j, 64);
            acc += wj * b2f(h2[(size_t)sj * 64 + lane]);
        }
    }
#pragma unroll
    for (int o = 32; o >= 1; o >>= 1) dsum += __shfl_xor(dsum, o, 64);
    float o = acc / (dsum + 1e-16f) + b2[lane];
    out[(size_t)dst * 64 + lane] = 1.f / (1.f + __expf(-o));
}

// ---------------- host ------------------------------------------------------

extern "C" void kernel_launch(void* const* d_in, const int* in_sizes, int n_in,
                              void* d_out, int out_size, void* d_ws, size_t ws_size,
                              hipStream_t stream) {
    const float* x    = (const float*)d_in[0];
    const void*  ei   = d_in[1];
    const float* W1   = (const float*)d_in[2];
    const float* asr1 = (const float*)d_in[3];
    const float* ads1 = (const float*)d_in[4];
    const float* b1   = (const float*)d_in[5];
    const float* W2   = (const float*)d_in[6];
    const float* asr2 = (const float*)d_in[7];
    const float* ads2 = (const float*)d_in[8];
    const float* b2   = (const float*)d_in[9];
    float* out = (float*)d_out;

    char* w = (char*)d_ws;
    auto carve = [&](size_t bytes) {
        void* p = (void*)w;
        w += (bytes + 255) & ~(size_t)255;
        return p;
    };
    int*    csr_raw  = (int*)carve((size_t)TE * 4);            // 3.4 MB
    int*    csr_can  = (int*)carve((size_t)TE * 4);            // 3.4 MB
    int*    offs     = (int*)carve((size_t)(NN + 1) * 4);
    int*    deg      = (int*)carve((size_t)NN * 4);
    int*    chunktot = (int*)carve(256 * 4);
    int*    chunkoff = (int*)carve(256 * 4);
    float*  a_src1   = (float*)carve((size_t)NN * 16 * 4);     // 3.2 MB
    float*  a_dst1   = (float*)carve((size_t)NN * 16 * 4);     // 3.2 MB
    unsigned short* W1T  = (unsigned short*)carve(128 * 256 * 2);  // 64 KB
    unsigned short* W2T  = (unsigned short*)carve(256 * 64 * 2);   // 32 KB
    unsigned short* P1sT = (unsigned short*)carve(16 * 128 * 2);   // 4 KB
    unsigned short* P1dT = (unsigned short*)carve(16 * 128 * 2);   // 4 KB
    unsigned short* P2T  = (unsigned short*)carve(16 * 256 * 2);   // 8 KB
    bf16*   h1       = (bf16*)carve((size_t)NN * 256 * 2);     // 25.6 MB
    bf16*   out1     = (bf16*)carve((size_t)NN * 256 * 2);     // 25.6 MB
    // layer-2 buffers alias h1 (dead after agg1)
    char*   l2base   = (char*)h1;
    bf16*   h2       = (bf16*)l2base;
    float*  a_src2   = (float*)(l2base + (size_t)NN * 64 * 2);
    float*  a_dst2   = a_src2 + NN;

    void* args[] = {
        (void*)&ei, (void*)&deg, (void*)&offs, (void*)&csr_raw,
        (void*)&chunktot, (void*)&chunkoff,
        (void*)&W1, (void*)&W2, (void*)&asr1, (void*)&ads1,
        (void*)&asr2, (void*)&ads2,
        (void*)&W1T, (void*)&W2T, (void*)&P1sT, (void*)&P1dT, (void*)&P2T,
    };
    hipLaunchCooperativeKernel((const void*)csr_build_k, dim3(CGRID), dim3(256),
                               args, 0, stream);

    gemm1_k<<<(NN + 63) / 64, 256, 0, stream>>>(x, W1T, P1sT, P1dT, h1, a_src1, a_dst1);
    agg1_k<<<NN / 4, 256, 0, stream>>>(offs, csr_raw, csr_can, a_src1, a_dst1, h1, b1, out1);
    gemm2_k<<<(NN + 63) / 64, 256, 0, stream>>>(out1, W2T, P2T, h2, a_src2, a_dst2);
    agg2_k<<<(NN + 3) / 4, 256, 0, stream>>>(offs, csr_can, a_src2, a_dst2, h2, b2, out);
}